// Round 3
// baseline (74.684 us; speedup 1.0000x reference)
//
#include <hip/hip_runtime.h>
#include <hip/hip_bf16.h>

// MultiScaleRoIAlign, two-phase:
//   Phase 1: NCHW f32 -> NHWC bf16 transpose of all 4 FPN levels into d_ws.
//            Makes every sampled cache line 100% useful (channels contiguous).
//   Phase 2: per-ROI sampler: 4 taps/bin x 256 contiguous bf16 channels,
//            bilinear in f32, LDS transpose back to [C][7][7], coalesced store.
// Level select: lvl = clip(floor(4 + log2(sqrt(area)/224 + 1e-8)), 2, 5) - 2
// ALIGNED=False, roi w/h >= 1, validity mask (s > -1 && s < H) else 0.

#define C_DIM 256
#define OUTB 7
#define NBINS 49
#define PER_ROI 12544   // 256*49
#define NROI 512

// ws layout (ushort/bf16 element offsets), NHWC per level: [n][h][w][c]
#define B0 0u
#define B1 33554432u    // B0 + 2*65536*256
#define B2 41943040u    // B1 + 2*16384*256
#define B3 44040192u    // B2 + 2*4096*256
#define WS_ELEMS 44564480u
#define WS_BYTES ((size_t)WS_ELEMS * 2)

__device__ __forceinline__ float bf_lo(unsigned u) { return __uint_as_float(u << 16); }
__device__ __forceinline__ float bf_hi(unsigned u) { return __uint_as_float(u & 0xffff0000u); }

// ---------------- Phase 1: tiled transpose NCHW f32 -> NHWC bf16 ----------
// grid (2720, 8, 2), block (32, 8). 32x32 tiles over (hw, c).
__global__ __launch_bounds__(256) void transpose_k(
    const float* __restrict__ f0, const float* __restrict__ f1,
    const float* __restrict__ f2, const float* __restrict__ f3,
    ushort* __restrict__ ws) {
  int bx = blockIdx.x;
  const float* __restrict__ src;
  unsigned base; int HW;
  if (bx < 2048)      { src = f0; base = B0; HW = 65536; }
  else if (bx < 2560) { src = f1; base = B1; HW = 16384; bx -= 2048; }
  else if (bx < 2688) { src = f2; base = B2; HW = 4096;  bx -= 2560; }
  else                { src = f3; base = B3; HW = 1024;  bx -= 2688; }
  const int hw0 = bx * 32, c0 = blockIdx.y * 32, n = blockIdx.z;
  const int tx = threadIdx.x, ty = threadIdx.y;

  __shared__ float t[32][33];  // +1 pad: conflict-free transposed reads
  const float* __restrict__ s = src + (size_t)n * C_DIM * HW;
#pragma unroll
  for (int i = 0; i < 4; i++)
    t[ty + 8 * i][tx] = s[(size_t)(c0 + ty + 8 * i) * HW + hw0 + tx];
  __syncthreads();
#pragma unroll
  for (int i = 0; i < 4; i++) {
    __hip_bfloat16 h = __float2bfloat16(t[tx][ty + 8 * i]);
    ws[base + ((size_t)n * HW + hw0 + ty + 8 * i) * C_DIM + c0 + tx] =
        *reinterpret_cast<ushort*>(&h);
  }
}

// ---------------- Phase 2: per-ROI NHWC sampler ---------------------------
// grid (512), block (256). Threads 0..127: even bins, 128..255: odd bins;
// each thread handles 2 adjacent channels (ushort2 taps).
__global__ __launch_bounds__(256) void sample_k(
    const ushort* __restrict__ ws, const float* __restrict__ boxes,
    float* __restrict__ out) {
  const int r = blockIdx.x, n = r >> 8, tid = threadIdx.x;
  const float4 box = ((const float4*)boxes)[r];

  // uniform level select (exact reference arithmetic)
  float bw = fmaxf(box.z - box.x, 0.0f);
  float bh = fmaxf(box.w - box.y, 0.0f);
  float lv = floorf(4.0f + log2f(sqrtf(bw * bh) / 224.0f + 1e-8f));
  int lvl = (int)(fminf(fmaxf(lv, 2.0f), 5.0f)) - 2;
  int H; float scale; unsigned base;
  switch (lvl) {
    case 0:  H = 256; scale = 0.25f;    base = B0; break;
    case 1:  H = 128; scale = 0.125f;   base = B1; break;
    case 2:  H = 64;  scale = 0.0625f;  base = B2; break;
    default: H = 32;  scale = 0.03125f; base = B3; break;
  }
  const int W = H, HW = H * W, W256 = W * C_DIM;
  const ushort* __restrict__ fb = ws + base + (size_t)n * HW * C_DIM;

  __shared__ int   g_off[NBINS];
  __shared__ float g_ly[NBINS], g_lx[NBINS], g_v[NBINS];
  __shared__ float obuf[PER_ROI];  // [c][bin] flat = c*49 + b (49 KB)

  if (tid < NBINS) {
    const int py = tid / OUTB, px = tid - py * OUTB;
    const float x1 = box.x * scale, y1 = box.y * scale;
    const float x2 = box.z * scale, y2 = box.w * scale;
    const float rw = fmaxf(x2 - x1, 1.0f), rh = fmaxf(y2 - y1, 1.0f);
    const float binw = rw / (float)OUTB, binh = rh / (float)OUTB;
    // boundary-sensitive: no fma contraction (must match numpy for the mask)
    const float ysf = __fadd_rn(y1, __fmul_rn((float)py + 0.5f, binh));
    const float xsf = __fadd_rn(x1, __fmul_rn((float)px + 0.5f, binw));
    const bool vy = (ysf > -1.0f) && (ysf < (float)H);
    const bool vx = (xsf > -1.0f) && (xsf < (float)W);
    float y = fminf(fmaxf(ysf, 0.0f), (float)(H - 1));
    float x = fminf(fmaxf(xsf, 0.0f), (float)(W - 1));
    int y0 = min((int)floorf(y), H - 2);
    int x0 = min((int)floorf(x), W - 2);
    g_off[tid] = (y0 * W + x0) * C_DIM;
    g_ly[tid]  = y - (float)y0;
    g_lx[tid]  = x - (float)x0;
    g_v[tid]   = (vy && vx) ? 1.0f : 0.0f;
  }
  __syncthreads();

  const int hi = tid >> 7;           // bin parity
  const int c2 = (tid & 127) * 2;    // channel pair

  unsigned a00, a01, a10, a11;
  float ly, lx, vm;
  auto load = [&](int i, unsigned& b00, unsigned& b01, unsigned& b10,
                  unsigned& b11, float& l_y, float& l_x, float& v_) {
    const int b = 2 * i + hi;
    if (b < NBINS) {
      const ushort* p = fb + g_off[b] + c2;
      b00 = *(const unsigned*)p;
      b01 = *(const unsigned*)(p + C_DIM);
      b10 = *(const unsigned*)(p + W256);
      b11 = *(const unsigned*)(p + W256 + C_DIM);
      l_y = g_ly[b]; l_x = g_lx[b]; v_ = g_v[b];
    } else {
      b00 = b01 = b10 = b11 = 0u; l_y = l_x = v_ = 0.0f;
    }
  };

  load(0, a00, a01, a10, a11, ly, lx, vm);
  for (int i = 0; i < 25; i++) {
    unsigned n00, n01, n10, n11; float nly, nlx, nv;
    load(i + 1, n00, n01, n10, n11, nly, nlx, nv);  // i=24 -> b>=49 -> zeros
    const int b = 2 * i + hi;
    if (b < NBINS) {
      const float wy0 = 1.0f - ly, wx0 = 1.0f - lx;
      float vl = wy0 * (wx0 * bf_lo(a00) + lx * bf_lo(a01)) +
                 ly  * (wx0 * bf_lo(a10) + lx * bf_lo(a11));
      float vh = wy0 * (wx0 * bf_hi(a00) + lx * bf_hi(a01)) +
                 ly  * (wx0 * bf_hi(a10) + lx * bf_hi(a11));
      obuf[c2 * NBINS + b]       = vl * vm;
      obuf[(c2 + 1) * NBINS + b] = vh * vm;
    }
    a00 = n00; a01 = n01; a10 = n10; a11 = n11;
    ly = nly; lx = nlx; vm = nv;
  }
  __syncthreads();

  float* __restrict__ o = out + (size_t)r * PER_ROI;
#pragma unroll
  for (int k = 0; k < NBINS; k++)
    o[k * 256 + tid] = obuf[k * 256 + tid];
}

// ---------------- Fallback (round-2 direct kernel) ------------------------
#define RLANES 256
#define NXCD 8
#define ROI_PER_XCD (NROI / NXCD)

__global__ __launch_bounds__(RLANES) void msroi_direct(
    const float* __restrict__ f0, const float* __restrict__ f1,
    const float* __restrict__ f2, const float* __restrict__ f3,
    const float* __restrict__ boxes, float* __restrict__ out) {
  const int wg = blockIdx.x;
  const int xcd = wg & (NXCD - 1);
  const int slot = wg >> 3;
  const int rr = slot / NBINS;
  const int blk = slot - rr * NBINS;
  const int r = xcd * ROI_PER_XCD + rr;
  const int le = blk * RLANES + threadIdx.x;
  const int c = le / NBINS;
  const int bin = le - c * NBINS;
  const int py = bin / OUTB, px = bin - py * OUTB;
  const int n = r >> 8;
  const float4 box = ((const float4*)boxes)[r];
  float bw = fmaxf(box.z - box.x, 0.0f), bh = fmaxf(box.w - box.y, 0.0f);
  float lv = floorf(4.0f + log2f(sqrtf(bw * bh) / 224.0f + 1e-8f));
  int lvl = (int)(fminf(fmaxf(lv, 2.0f), 5.0f)) - 2;
  const float* __restrict__ feat; int H; float scale;
  switch (lvl) {
    case 0:  feat = f0; H = 256; scale = 0.25f;    break;
    case 1:  feat = f1; H = 128; scale = 0.125f;   break;
    case 2:  feat = f2; H = 64;  scale = 0.0625f;  break;
    default: feat = f3; H = 32;  scale = 0.03125f; break;
  }
  const int W = H;
  const float x1 = box.x * scale, y1 = box.y * scale;
  const float x2 = box.z * scale, y2 = box.w * scale;
  const float rw = fmaxf(x2 - x1, 1.0f), rh = fmaxf(y2 - y1, 1.0f);
  const float binw = rw / (float)OUTB, binh = rh / (float)OUTB;
  const float ysf = __fadd_rn(y1, __fmul_rn((float)py + 0.5f, binh));
  const float xsf = __fadd_rn(x1, __fmul_rn((float)px + 0.5f, binw));
  const bool vy = (ysf > -1.0f) && (ysf < (float)H);
  const bool vx = (xsf > -1.0f) && (xsf < (float)W);
  float y = fminf(fmaxf(ysf, 0.0f), (float)(H - 1));
  float x = fminf(fmaxf(xsf, 0.0f), (float)(W - 1));
  int y0 = min((int)floorf(y), H - 2);
  int x0 = min((int)floorf(x), W - 2);
  const float lyv = y - (float)y0, lxv = x - (float)x0;
  const float* __restrict__ p =
      feat + (((size_t)n * C_DIM + c) * (size_t)H + y0) * (size_t)W + x0;
  const float2 v0 = *reinterpret_cast<const float2*>(p);
  const float2 v1 = *reinterpret_cast<const float2*>(p + W);
  const float wx0 = 1.0f - lxv;
  float val = (1.0f - lyv) * (wx0 * v0.x + lxv * v0.y) +
              lyv * (wx0 * v1.x + lxv * v1.y);
  val = (vy && vx) ? val : 0.0f;
  out[(size_t)r * PER_ROI + le] = val;
}

extern "C" void kernel_launch(void* const* d_in, const int* in_sizes, int n_in,
                              void* d_out, int out_size, void* d_ws, size_t ws_size,
                              hipStream_t stream) {
  const float* f0 = (const float*)d_in[0];
  const float* f1 = (const float*)d_in[1];
  const float* f2 = (const float*)d_in[2];
  const float* f3 = (const float*)d_in[3];
  const float* boxes = (const float*)d_in[4];
  float* out = (float*)d_out;

  if (ws_size >= WS_BYTES) {
    ushort* ws = (ushort*)d_ws;
    dim3 tg(2720, 8, 2), tb(32, 8);
    transpose_k<<<tg, tb, 0, stream>>>(f0, f1, f2, f3, ws);
    sample_k<<<NROI, 256, 0, stream>>>(ws, boxes, out);
  } else {
    msroi_direct<<<NROI * NBINS, RLANES, 0, stream>>>(f0, f1, f2, f3, boxes, out);
  }
}

// Round 4
// 43.889 us; speedup vs baseline: 1.7017x; 1.7017x over previous
//
#include <hip/hip_runtime.h>
#include <hip/hip_bf16.h>

// MultiScaleRoIAlign for FPN, direct gather (NCHW f32).
//   feats: stride {4,8,16,32} -> (2,256,256,256)/(2,256,128,128)/(2,256,64,64)/(2,256,32,32)
//   boxes: (2,256,4) xyxy, IMG=1024; out: (512,256,7,7) f32
// Level: lvl = clip(floor(4 + log2(sqrt(area)/224 + 1e-8)), 2, 5) - 2
// ALIGNED=False, roi w/h >= 1, mask (s > -1 && s < H) else 0.
//
// Structure: 1 thread = 1 bin x 4 channels (c4, c4+64, c4+128, c4+192).
// Tap coords are channel-invariant -> coord math amortized 4x, 8 independent
// gathers per thread (4x MLP vs 1-channel version). XCD swizzle keeps each
// ROI's window set on one XCD's L2.

#define C_DIM 256
#define OUTB 7
#define NBINS 49
#define PER_ROI 12544        // 256*49
#define NROI 512
#define CQ 64                // channel quarters
#define TPB 256
#define BLK_PER_ROI 13       // ceil(64*49 / 256)
#define NXCD 8
#define ROI_PER_XCD (NROI / NXCD)   // 64

__global__ __launch_bounds__(TPB) void msroi4_kernel(
    const float* __restrict__ f0, const float* __restrict__ f1,
    const float* __restrict__ f2, const float* __restrict__ f3,
    const float* __restrict__ boxes, float* __restrict__ out) {
  // 6656 blocks = 8 XCDs x 832 (= 64 rois x 13 blocks). Consecutive blockIdx
  // round-robin XCDs; give XCD k rois [64k, 64k+64).
  const int wg   = blockIdx.x;
  const int xcd  = wg & (NXCD - 1);
  const int slot = wg >> 3;                 // 0..831
  const int rr   = slot / BLK_PER_ROI;      // 0..63
  const int blk  = slot - rr * BLK_PER_ROI; // 0..12
  const int r    = xcd * ROI_PER_XCD + rr;

  const int le = blk * TPB + threadIdx.x;   // 0..3327; valid < 3136
  if (le >= CQ * NBINS) return;
  const int c4  = le / NBINS;               // 0..63
  const int bin = le - c4 * NBINS;
  const int py  = bin / OUTB;
  const int px  = bin - py * OUTB;

  const int n = r >> 8;                     // 256 rois per image

  const float4 box = ((const float4*)boxes)[r];

  // ---- level selection (exact reference arithmetic) ----
  float bw = fmaxf(box.z - box.x, 0.0f);
  float bh = fmaxf(box.w - box.y, 0.0f);
  float lv = floorf(4.0f + log2f(sqrtf(bw * bh) / 224.0f + 1e-8f));
  const int lvl = (int)(fminf(fmaxf(lv, 2.0f), 5.0f)) - 2;  // 0..3

  const float* __restrict__ feat;
  switch (lvl) {
    case 0:  feat = f0; break;
    case 1:  feat = f1; break;
    case 2:  feat = f2; break;
    default: feat = f3; break;
  }
  const int sh = 8 - lvl;        // W = H = 1 << sh
  const int H  = 1 << sh;
  const int W  = H;
  const float scale = 1.0f / (float)(4 << lvl);

  // ---- ROI geometry ----
  const float x1 = box.x * scale, y1 = box.y * scale;
  const float x2 = box.z * scale, y2 = box.w * scale;
  const float roi_w = fmaxf(x2 - x1, 1.0f);
  const float roi_h = fmaxf(y2 - y1, 1.0f);
  const float bin_w = roi_w / (float)OUTB;
  const float bin_h = roi_h / (float)OUTB;

  // Boundary-sensitive: no fma contraction (mask must match numpy exactly).
  const float ysf = __fadd_rn(y1, __fmul_rn((float)py + 0.5f, bin_h));
  const float xsf = __fadd_rn(x1, __fmul_rn((float)px + 0.5f, bin_w));
  const bool vy = (ysf > -1.0f) && (ysf < (float)H);
  const bool vx = (xsf > -1.0f) && (xsf < (float)W);
  const float vm = (vy && vx) ? 1.0f : 0.0f;

  float y = fminf(fmaxf(ysf, 0.0f), (float)(H - 1));
  float x = fminf(fmaxf(xsf, 0.0f), (float)(W - 1));
  const int y0 = min((int)floorf(y), H - 2);
  const int x0 = min((int)floorf(x), W - 2);
  const float ly = y - (float)y0;
  const float lx = x - (float)x0;
  const float wy0 = 1.0f - ly, wx0 = 1.0f - lx;

  // plane address: ((n*256 + c)*H + y0)*W + x0, with W,HW as shifts
  const int hw_sh = 2 * sh;
  const size_t pofs = (((size_t)(n * C_DIM + c4) << hw_sh) + ((size_t)y0 << sh)) + (size_t)x0;
  const size_t cstep = (size_t)CQ << hw_sh;  // 64 channel planes
  const float* __restrict__ p = feat + pofs;

  // 8 independent gathers (compiler hoists all loads -> max MLP)
  float2 a0 = *reinterpret_cast<const float2*>(p);
  float2 b0 = *reinterpret_cast<const float2*>(p + W);
  float2 a1 = *reinterpret_cast<const float2*>(p + cstep);
  float2 b1 = *reinterpret_cast<const float2*>(p + cstep + W);
  float2 a2 = *reinterpret_cast<const float2*>(p + 2 * cstep);
  float2 b2 = *reinterpret_cast<const float2*>(p + 2 * cstep + W);
  float2 a3 = *reinterpret_cast<const float2*>(p + 3 * cstep);
  float2 b3 = *reinterpret_cast<const float2*>(p + 3 * cstep + W);

  float* __restrict__ o = out + (size_t)r * PER_ROI + le;  // le = c4*49+bin
  const float s0 = vm * (wy0 * (wx0 * a0.x + lx * a0.y) + ly * (wx0 * b0.x + lx * b0.y));
  const float s1 = vm * (wy0 * (wx0 * a1.x + lx * a1.y) + ly * (wx0 * b1.x + lx * b1.y));
  const float s2 = vm * (wy0 * (wx0 * a2.x + lx * a2.y) + ly * (wx0 * b2.x + lx * b2.y));
  const float s3 = vm * (wy0 * (wx0 * a3.x + lx * a3.y) + ly * (wx0 * b3.x + lx * b3.y));
  o[0]              = s0;
  o[CQ * NBINS]     = s1;   // +64 channels
  o[2 * CQ * NBINS] = s2;
  o[3 * CQ * NBINS] = s3;
}

extern "C" void kernel_launch(void* const* d_in, const int* in_sizes, int n_in,
                              void* d_out, int out_size, void* d_ws, size_t ws_size,
                              hipStream_t stream) {
  const float* f0 = (const float*)d_in[0];
  const float* f1 = (const float*)d_in[1];
  const float* f2 = (const float*)d_in[2];
  const float* f3 = (const float*)d_in[3];
  const float* boxes = (const float*)d_in[4];
  float* out = (float*)d_out;

  dim3 grid(NXCD * ROI_PER_XCD * BLK_PER_ROI);  // 6656
  dim3 block(TPB);
  msroi4_kernel<<<grid, block, 0, stream>>>(f0, f1, f2, f3, boxes, out);
}